// Round 1
// baseline (110.646 us; speedup 1.0000x reference)
//
#include <hip/hip_runtime.h>

// Kernel 1: per-group 2x2 matrix M[g] = R(phase[g]) * polar(W[g]).
// Closed-form polar projection of a 2x2 real matrix (= U @ Vh from SVD):
//   det >= 0: nearest rotation   Q = normalize([[a+d, b-c],[c-b, a+d]])
//   det <  0: nearest reflection Q = normalize([[a-d, b+c],[b+c, d-a]])
__global__ void bsu_compute_M(const float* __restrict__ W,
                              const float* __restrict__ phase,
                              float4* __restrict__ M, int G) {
    int g = blockIdx.x * blockDim.x + threadIdx.x;
    if (g >= G) return;
    float a = W[4 * g + 0];
    float b = W[4 * g + 1];
    float c = W[4 * g + 2];
    float d = W[4 * g + 3];
    float det = a * d - b * c;
    float q00, q01, q10, q11;
    if (det >= 0.0f) {
        float p = a + d;
        float q = b - c;
        float inv = rsqrtf(p * p + q * q);
        q00 = p * inv;  q01 = q * inv;
        q10 = -q * inv; q11 = p * inv;
    } else {
        float p = a - d;
        float q = b + c;
        float inv = rsqrtf(p * p + q * q);
        q00 = p * inv; q01 = q * inv;
        q10 = q * inv; q11 = -p * inv;
    }
    float cs, sn;
    __sincosf(phase[g], &sn, &cs);
    float4 m;
    m.x = cs * q00 - sn * q10;  // M00
    m.y = cs * q01 - sn * q11;  // M01
    m.z = sn * q00 + cs * q10;  // M10
    m.w = sn * q01 + cs * q11;  // M11
    M[g] = m;
}

// Kernel 2: streaming apply. Each lane handles one float4 = two (x0,x1) pairs.
// Flat pair index p = 2*i; group = p & (G-1) (C == 2*G, G power of two).
// Second pair's group is always g+1: 2*i is even, so (2*i)&(G-1) <= G-2.
__global__ __launch_bounds__(256) void bsu_apply(const float4* __restrict__ x,
                                                 const float4* __restrict__ M,
                                                 float4* __restrict__ y,
                                                 int n4, int gmask) {
    int i = blockIdx.x * blockDim.x + threadIdx.x;
    int stride = gridDim.x * blockDim.x;
    for (; i < n4; i += stride) {
        float4 v = x[i];
        int g0 = (2 * i) & gmask;
        float4 m0 = M[g0];
        float4 m1 = M[g0 + 1];
        float4 o;
        o.x = m0.x * v.x + m0.y * v.y;
        o.y = m0.z * v.x + m0.w * v.y;
        o.z = m1.x * v.z + m1.y * v.w;
        o.w = m1.z * v.z + m1.w * v.w;
        y[i] = o;
    }
}

extern "C" void kernel_launch(void* const* d_in, const int* in_sizes, int n_in,
                              void* d_out, int out_size, void* d_ws, size_t ws_size,
                              hipStream_t stream) {
    const float* x     = (const float*)d_in[0];   // [B,T,C] f32
    const float* Wp    = (const float*)d_in[1];   // [G,2,2] f32
    const float* phase = (const float*)d_in[2];   // [G] f32
    float* y = (float*)d_out;

    int G = in_sizes[2];            // 1024
    int n = in_sizes[0];            // B*T*C
    int n4 = n / 4;

    float4* M = (float4*)d_ws;      // G * 16 bytes = 16 KB scratch

    bsu_compute_M<<<(G + 255) / 256, 256, 0, stream>>>(Wp, phase, M, G);

    int blocks = (n4 + 255) / 256;
    if (blocks > 2048) blocks = 2048;
    bsu_apply<<<blocks, 256, 0, stream>>>((const float4*)x, M, (float4*)y,
                                          n4, G - 1);
}

// Round 2
// 99.706 us; speedup vs baseline: 1.1097x; 1.1097x over previous
//
#include <hip/hip_runtime.h>

typedef float f32x4 __attribute__((ext_vector_type(4)));

// Closed-form polar projection of 2x2 W (= U @ Vh from SVD), then compose
// with phase rotation R(phi) = [[c,-s],[s,c]]:  M = R * polar(W).
__device__ __forceinline__ void compute_M(const float4* __restrict__ W,
                                          const float* __restrict__ phase,
                                          int g,
                                          float& m00, float& m01,
                                          float& m10, float& m11) {
    float4 w = W[g];                 // [a b; c d] row-major
    float a = w.x, b = w.y, c = w.z, d = w.w;
    float det = a * d - b * c;
    float q00, q01, q10, q11;
    if (det >= 0.0f) {               // nearest rotation
        float p = a + d, q = b - c;
        float inv = rsqrtf(p * p + q * q);
        q00 = p * inv;  q01 = q * inv;
        q10 = -q * inv; q11 = p * inv;
    } else {                         // nearest reflection
        float p = a - d, q = b + c;
        float inv = rsqrtf(p * p + q * q);
        q00 = p * inv; q01 = q * inv;
        q10 = q * inv; q11 = -p * inv;
    }
    float cs, sn;
    __sincosf(phase[g], &sn, &cs);
    m00 = cs * q00 - sn * q10;
    m01 = cs * q01 - sn * q11;
    m10 = sn * q00 + cs * q10;
    m11 = sn * q01 + cs * q11;
}

// Fused streaming kernel. Each lane handles one float4 = two (x0,x1) pairs.
// Grid-stride is chosen a multiple of (C/4) float4s, so each thread's group
// index g0 = (2*i) & (G-1) is LOOP-INVARIANT: compute the two 2x2 matrices
// once in registers, then run a pure load -> 4 fma -> store stream.
__global__ __launch_bounds__(256) void bsu_fused(const f32x4* __restrict__ x,
                                                 const float4* __restrict__ W,
                                                 const float* __restrict__ phase,
                                                 f32x4* __restrict__ y,
                                                 int n4, int gmask) {
    int i0 = blockIdx.x * 256 + threadIdx.x;
    int stride = gridDim.x * 256;
    int g0 = (2 * i0) & gmask;       // even -> g0+1 never wraps

    float a00, a01, a10, a11;        // M[g0]
    float b00, b01, b10, b11;        // M[g0+1]
    compute_M(W, phase, g0,     a00, a01, a10, a11);
    compute_M(W, phase, g0 + 1, b00, b01, b10, b11);

    for (int i = i0; i < n4; i += stride) {
        f32x4 v = __builtin_nontemporal_load(&x[i]);
        f32x4 o;
        o.x = a00 * v.x + a01 * v.y;
        o.y = a10 * v.x + a11 * v.y;
        o.z = b00 * v.z + b01 * v.w;
        o.w = b10 * v.z + b11 * v.w;
        __builtin_nontemporal_store(o, &y[i]);
    }
}

extern "C" void kernel_launch(void* const* d_in, const int* in_sizes, int n_in,
                              void* d_out, int out_size, void* d_ws, size_t ws_size,
                              hipStream_t stream) {
    const float* x     = (const float*)d_in[0];   // [B,T,C] f32
    const float* Wp    = (const float*)d_in[1];   // [G,2,2] f32
    const float* phase = (const float*)d_in[2];   // [G] f32
    float* y = (float*)d_out;

    int G = in_sizes[2];             // 1024
    int n = in_sizes[0];             // B*T*C = 67,108,864
    int n4 = n / 4;                  // 16,777,216 float4s

    // 2048 blocks * 256 threads = 524288 = 1024 * (G/2) -> stride is a
    // multiple of float4s-per-row, keeping g0 loop-invariant per thread.
    int blocks = 2048;
    int row4 = G / 2;                // float4s per C-row
    // Defensive: if stride wouldn't divide the row, fall back to exact cover.
    if ((blocks * 256) % row4 != 0) blocks = (n4 + 255) / 256;

    bsu_fused<<<blocks, 256, 0, stream>>>((const f32x4*)x, (const float4*)Wp,
                                          phase, (f32x4*)y, n4, G - 1);
}